// Round 14
// baseline (36.848 us; speedup 1.0000x reference)
//
#include <hip/hip_runtime.h>

typedef _Float16 h8     __attribute__((ext_vector_type(8)));
typedef float    f32x16 __attribute__((ext_vector_type(16)));

#define BB      16
#define NPTS    4096
#define WAVES   4                       // waves per block
#define RPW     64                      // rows per wave = 2 row-blocks of 32
#define RPB     (WAVES * RPW)           // 256 rows per block
#define CSPLIT  2                       // column split across blocks
#define COLS    (NPTS / CSPLIT)         // 2048 cols per block
#define CHUNK   512                     // cols staged per LDS chunk
#define NCHUNK  (COLS / CHUNK)          // 4
#define NT      (CHUNK / 32)            // 16 b-tiles per chunk
#define SEGS    4                       // 1KB gload_lds segments per wave per chunk
#define TPB     (WAVES * 64)            // 256

// ---- prep: fp32 xyz -> fp16-split A/B operand tables in ws; also init out ----
// A[p] (per-point contiguous 16 halfs):
//   [xh,yh,zh,xh,yh,zh,xl,yl | zl,s1h,s1l,1,1,0,0,0]
// B written in the TILED layout the MFMA sweep reads (R13 bug: it was
// per-point contiguous; global_load_lds copies linearly so global order MUST
// equal LDS order): point p -> tile g=p>>5, slot cc=p&31:
//   half0 [-2xh,-2yh,-2zh,-2xl,-2yl,-2zl,-2xh,-2yh] at g*512 + cc*8
//   half1 [-2zh,1,1,s2h,s2l,0,0,0]                  at g*512 + 256 + cc*8
// (K=13 fp16-split dot, proven R6-R12, absmax ~1e-3)
__global__ __launch_bounds__(256) void chamfer_prep(
    const float* __restrict__ xyz1, const float* __restrict__ xyz2,
    _Float16* __restrict__ Aws, _Float16* __restrict__ Bws,
    float* __restrict__ out)
{
    const int idx = blockIdx.x * 256 + threadIdx.x;   // 0..131071 = [s][b][p]
    out[idx] = 3.0e38f;                               // init output (harness poisons)
    const int s   = idx >> 16;                        // set 0/1
    const int rem = idx & 65535;
    const float* p = (s == 0 ? xyz1 : xyz2) + rem * 3;
    float x = p[0], y = p[1], z = p[2];
    float ss = fmaf(x, x, fmaf(y, y, z * z));
    _Float16 xh = (_Float16)x, yh = (_Float16)y, zh = (_Float16)z;
    _Float16 xl = (_Float16)(x - (float)xh);
    _Float16 yl = (_Float16)(y - (float)yh);
    _Float16 zl = (_Float16)(z - (float)zh);
    _Float16 sh = (_Float16)ss;
    _Float16 sl = (_Float16)(ss - (float)sh);
    _Float16 one = (_Float16)1.0f, zero = (_Float16)0.0f;
    _Float16 m2xh = (_Float16)(-2.0f) * xh;
    _Float16 m2yh = (_Float16)(-2.0f) * yh;
    _Float16 m2zh = (_Float16)(-2.0f) * zh;
    _Float16 m2xl = (_Float16)(-2.0f * (x - (float)xh));
    _Float16 m2yl = (_Float16)(-2.0f * (y - (float)yh));
    _Float16 m2zl = (_Float16)(-2.0f * (z - (float)zh));

    _Float16* A = Aws + (size_t)idx * 16;
    *(h8*)(A)     = h8{xh, yh, zh, xh, yh, zh, xl, yl};
    *(h8*)(A + 8) = h8{zl, sh, sl, one, one, zero, zero, zero};

    const int pp = idx & 4095;                        // point within batch
    const int slab = idx >> 12;                       // s*16 + b
    _Float16* B = Bws + (size_t)slab * (NPTS * 16) + (pp >> 5) * 512 + (pp & 31) * 8;
    *(h8*)(B)       = h8{m2xh, m2yh, m2zh, m2xl, m2yl, m2zl, m2xh, m2yh};
    *(h8*)(B + 256) = h8{m2zh, one, one, sh, sl, zero, zero, zero};
}

// ---- main: gload_lds-staged MFMA sweep, zero staging VALU ----
// LDS sb: tile t, k-half hf, col c: half-off = t*512 + hf*256 + (c&31)*8
//  == the global B layout (prep writes it tiled), so the linear
//  global_load_lds copy is correct and wave ds_read_b128 stays linear
//  1024B, conflict-free (verified R7/R8).
__global__ __launch_bounds__(TPB, 4) void chamfer_mfma(
    const _Float16* __restrict__ Aws,
    const _Float16* __restrict__ Bws,
    float* __restrict__ out)
{
    __shared__ __align__(16) _Float16 sb[2][CHUNK * 16];   // 2 x 16 KB

    const int tid  = threadIdx.x;
    const int lane = tid & 63;
    const int wv   = tid >> 6;
    const int rb   = blockIdx.x;       // row-block 0..15
    const int b    = blockIdx.y;       // batch
    const int z    = blockIdx.z;       // dir + col-split
    const int dir  = z & 1;            // 0: rows=set1/cols=set2, 1: reverse
    const int csp  = z >> 1;           // 0..CSPLIT-1

    // ---- A fragments: two h8 vector loads per row-block ----
    h8 af0, af1;
    {
        const _Float16* Abase = Aws + ((size_t)dir << 20) + (size_t)b * (NPTS * 16);
        const int r0 = rb * RPB + wv * RPW + (lane & 31);
        const int hs = (lane >> 5) * 8;
        af0 = *(const h8*)(Abase + (size_t)r0 * 16 + hs);
        af1 = *(const h8*)(Abase + (size_t)(r0 + 32) * 16 + hs);
    }
    const _Float16* Bbase = Bws + ((size_t)(dir ^ 1) << 20) + (size_t)b * (NPTS * 16)
                          + (size_t)csp * (COLS * 16);

    const f32x16 Z = {};
    float rm0[16], rm1[16];
#pragma unroll
    for (int r = 0; r < 16; ++r) { rm0[r] = 3.0e38f; rm1[r] = 3.0e38f; }

    const int loff = ((lane >> 5) << 8) + (lane & 31) * 8;   // halfs

    // ---- staging: async global->LDS, 1KB per call, no VALU ----
    auto stage = [&](int ch, int buf) {
        const char* g = (const char*)(Bbase + (size_t)ch * CHUNK * 16);
        char* l = (char*)&sb[buf][0];
#pragma unroll
        for (int j = 0; j < SEGS; ++j) {
            int seg = wv * SEGS + j;
            __builtin_amdgcn_global_load_lds(
                (const unsigned int*)(g + seg * 1024 + lane * 16),
                (unsigned int*)(l + seg * 1024), 16, 0, 0);
        }
    };

    // ---- sweep: 2 tiles per step; pair-fold invites v_min3_f32 ----
    auto sweep = [&](int buf) {
        const _Float16* base = &sb[buf][0];
#pragma unroll 1
        for (int t = 0; t < NT; t += 2) {
            h8 bx = *(const h8*)(base + t * 512 + loff);
            h8 by = *(const h8*)(base + (t + 1) * 512 + loff);
            f32x16 c0 = __builtin_amdgcn_mfma_f32_32x32x16_f16(af0, bx, Z, 0, 0, 0);
            f32x16 c1 = __builtin_amdgcn_mfma_f32_32x32x16_f16(af0, by, Z, 0, 0, 0);
            f32x16 d0 = __builtin_amdgcn_mfma_f32_32x32x16_f16(af1, bx, Z, 0, 0, 0);
            f32x16 d1 = __builtin_amdgcn_mfma_f32_32x32x16_f16(af1, by, Z, 0, 0, 0);
#pragma unroll
            for (int r = 0; r < 16; ++r)
                rm0[r] = fminf(fminf(c0[r], c1[r]), rm0[r]);   // v_min3_f32 candidate
#pragma unroll
            for (int r = 0; r < 16; ++r)
                rm1[r] = fminf(fminf(d0[r], d1[r]), rm1[r]);
        }
    };

    stage(0, 0);
    __syncthreads();                    // compiler drains vmcnt(0) before barrier
#pragma unroll 1
    for (int ch = 0; ch < NCHUNK; ++ch) {
        int buf = ch & 1;
        if (ch + 1 < NCHUNK) stage(ch + 1, buf ^ 1);   // async, overlaps sweep
        sweep(buf);
        __syncthreads();                // next buffer complete + this one free
    }

    // ---- reduce over 32 col-lanes (butterfly within each half) ----
#pragma unroll
    for (int r = 0; r < 16; ++r) {
        float m = rm0[r];
        m = fminf(m, __shfl_xor(m, 1));
        m = fminf(m, __shfl_xor(m, 2));
        m = fminf(m, __shfl_xor(m, 4));
        m = fminf(m, __shfl_xor(m, 8));
        m = fminf(m, __shfl_xor(m, 16));
        rm0[r] = m;
        float n = rm1[r];
        n = fminf(n, __shfl_xor(n, 1));
        n = fminf(n, __shfl_xor(n, 2));
        n = fminf(n, __shfl_xor(n, 4));
        n = fminf(n, __shfl_xor(n, 8));
        n = fminf(n, __shfl_xor(n, 16));
        rm1[r] = n;
    }
    // ---- combine across col-splits via int atomicMin (values >= 0) ----
    if ((lane & 31) == 0) {
        const int half = lane >> 5;
        int* o = (int*)out + dir * (BB * NPTS) + b * NPTS + rb * RPB + wv * RPW;
#pragma unroll
        for (int r = 0; r < 16; ++r) {
            int rr = (r & 3) + 8 * (r >> 2) + 4 * half;   // C/D row map (m74/m101)
            atomicMin(o + rr,      __float_as_int(fmaxf(rm0[r], 0.0f)));
            atomicMin(o + 32 + rr, __float_as_int(fmaxf(rm1[r], 0.0f)));
        }
    }
}

extern "C" void kernel_launch(void* const* d_in, const int* in_sizes, int n_in,
                              void* d_out, int out_size, void* d_ws, size_t ws_size,
                              hipStream_t stream) {
    const float* xyz1 = (const float*)d_in[0];
    const float* xyz2 = (const float*)d_in[1];
    float* out = (float*)d_out;
    _Float16* Aws = (_Float16*)d_ws;                       // 2*16*4096*16 halfs = 4MB
    _Float16* Bws = Aws + (size_t)2 * BB * NPTS * 16;      // +4MB

    hipLaunchKernelGGL(chamfer_prep, dim3(2 * BB * NPTS / 256), dim3(256), 0, stream,
                       xyz1, xyz2, Aws, Bws, out);

    dim3 grid(NPTS / RPB, BB, 2 * CSPLIT);   // 16 x 16 x 4 = 1024 blocks
    hipLaunchKernelGGL(chamfer_mfma, grid, dim3(TPB), 0, stream, Aws, Bws, out);
}